// Round 7
// baseline (765.500 us; speedup 1.0000x reference)
//
#include <hip/hip_runtime.h>
#include <hip/hip_bf16.h>

#define NN 4096   // nodes
#define DE 16     // embedding dim
#define NH 4      // heads
#define LL 64     // in_dim
#define NB 16     // batch
#define CC 1024   // NB*LL columns

typedef __attribute__((ext_vector_type(8))) short short8v;
typedef __attribute__((ext_vector_type(4))) float f32x4;

#define GLD_LDS16(gp, lp) __builtin_amdgcn_global_load_lds( \
    (const __attribute__((address_space(1))) unsigned int*)(gp), \
    (__attribute__((address_space(3))) unsigned int*)(lp), 16, 0, 0)

__device__ __forceinline__ unsigned short f2bf(float f){
  unsigned int u = __float_as_uint(f);
  u += 0x7fffu + ((u >> 16) & 1u);
  return (unsigned short)(u >> 16);
}
__device__ __forceinline__ float bf2f(unsigned short s){
  return __uint_as_float(((unsigned int)s) << 16);
}
__device__ __forceinline__ void get_mix(const float* hm, float* mw){
  float a=hm[0],b=hm[1],c=hm[2],d=hm[3];
  float m = fmaxf(fmaxf(a,b),fmaxf(c,d));
  float e0=__expf(a-m),e1=__expf(b-m),e2=__expf(c-m),e3=__expf(d-m);
  float inv = 1.0f/(e0+e1+e2+e3);
  mw[0]=e0*inv; mw[1]=e1*inv; mw[2]=e2*inv; mw[3]=e3*inv;
}

// ---- K1a: per-node prep: Q/K projections as bf16 hi/lo splits, psi splits,
//          ||p||^2, combined bias ------------------------------------------
__global__ void k_prep(const float* __restrict__ psi_emb, const float* __restrict__ W_q,
                       const float* __restrict__ W_k, const float* __restrict__ f_b,
                       const float* __restrict__ head_mix,
                       unsigned short* __restrict__ Qh, unsigned short* __restrict__ Ql,
                       unsigned short* __restrict__ Kh, unsigned short* __restrict__ Kl,
                       unsigned short* __restrict__ Ph, unsigned short* __restrict__ Pl,
                       float* __restrict__ n2g, float* __restrict__ bias_comb){
  int n = blockIdx.x*blockDim.x + threadIdx.x;
  if (n >= NN) return;
  float p[DE];
  float n2 = 0.f;
  unsigned short ph[DE], pl[DE];
  #pragma unroll
  for (int d=0;d<DE;d++){
    p[d] = psi_emb[n*DE+d];
    n2 += p[d]*p[d];
    ph[d] = f2bf(p[d]);
    pl[d] = f2bf(p[d] - bf2f(ph[d]));
  }
  n2g[n] = n2;
  *(short8v*)(Ph + n*DE)     = *(short8v*)ph;
  *(short8v*)(Ph + n*DE + 8) = *(short8v*)(ph+8);
  *(short8v*)(Pl + n*DE)     = *(short8v*)pl;
  *(short8v*)(Pl + n*DE + 8) = *(short8v*)(pl+8);
  float mw[NH]; get_mix(head_mix, mw);
  float bias = 0.f;
  for (int h=0; h<NH; h++){
    unsigned short qh[DE], ql[DE], kh[DE], kl[DE];
    #pragma unroll
    for (int m=0;m<DE;m++){
      float q=0.f,k=0.f;
      #pragma unroll
      for (int d=0;d<DE;d++){
        q += p[d]*W_q[(d*NH+h)*DE+m];
        k += p[d]*W_k[(d*NH+h)*DE+m];
      }
      qh[m]=f2bf(q); ql[m]=f2bf(q - bf2f(qh[m]));
      kh[m]=f2bf(k); kl[m]=f2bf(k - bf2f(kh[m]));
    }
    size_t base = ((size_t)h*NN + n)*DE;
    *(short8v*)(Qh+base)=*(short8v*)qh;   *(short8v*)(Qh+base+8)=*(short8v*)(qh+8);
    *(short8v*)(Ql+base)=*(short8v*)ql;   *(short8v*)(Ql+base+8)=*(short8v*)(ql+8);
    *(short8v*)(Kh+base)=*(short8v*)kh;   *(short8v*)(Kh+base+8)=*(short8v*)(kh+8);
    *(short8v*)(Kl+base)=*(short8v*)kl;   *(short8v*)(Kl+base+8)=*(short8v*)(kl+8);
    float bh=0.f;
    #pragma unroll
    for (int d=0;d<DE;d++) bh += p[d]*f_b[h*DE+d];
    bias += mw[h]*bh;
  }
  bias_comb[n]=bias;
}

// ---- K1b: per-node filter weights Wf_eff[h][k][l][n] (premult by mix_w) ---
__global__ void k_wf(const float* __restrict__ psi_emb, const float* __restrict__ F_w,
                     const float* __restrict__ head_mix,
                     float* __restrict__ Wf_eff, float* __restrict__ W0c){
  int id = blockIdx.x*256 + threadIdx.x;   // 2^20 threads: (k,l,n)
  int n = id & (NN-1);
  int kl = id >> 12;
  int l = kl & (LL-1);
  int k = kl >> 6;                          // 0..3
  float mw[NH]; get_mix(head_mix, mw);
  float p[DE];
  #pragma unroll
  for (int d=0;d<DE;d++) p[d]=psi_emb[n*DE+d];
  float s0=0.f;
  for (int h=0;h<NH;h++){
    float v=0.f;
    #pragma unroll
    for (int d=0;d<DE;d++) v += p[d]*F_w[((h*DE+d)*4+k)*LL+l];
    v *= mw[h];
    Wf_eff[(((size_t)(h*4+k))*LL+l)*NN+n]=v;
    s0 += v;
  }
  if (k==0) W0c[(size_t)l*NN+n]=s0;
}

// ---- K2: fused adjacency build (stats sweep + write sweep), MFMA scores ---
__global__ __launch_bounds__(256, 4) void k_adj(
    const unsigned short* __restrict__ Qh, const unsigned short* __restrict__ Ql,
    const unsigned short* __restrict__ Kh, const unsigned short* __restrict__ Kl,
    const unsigned short* __restrict__ Ph, const unsigned short* __restrict__ Pl,
    const float* __restrict__ n2g, const float* __restrict__ psi_p,
    const float* __restrict__ attn_alpha, unsigned short* __restrict__ A_all){
  __shared__ unsigned short T[4][16][72];
  __shared__ float st_g[4][16], st_m[4][16], st_s[4][16];
  __shared__ float fin_g[16], fin_m[16], fin_s[16];

  int tid = threadIdx.x;
  int lane = tid & 63, w = tid >> 6;
  int h = blockIdx.y;
  int n0 = blockIdx.x * 16;
  int kg = lane >> 4;          // k-group 0..3
  int cl = lane & 15;          // col-in-tile / row-in-frag
  float psi_v = psi_p[0];
  float alpha = 1.f/(1.f+__expf(-attn_alpha[0]));

  short8v z8 = {};
  int rown = n0 + cl;
  const unsigned short* qb = ((kg<2) ? Qh : Ql) + ((size_t)h*NN + rown)*DE + (kg&1)*8;
  const unsigned short* pb = ((kg<2) ? Ph : Pl) + (size_t)rown*DE + (kg&1)*8;
  short8v aF1 = *(const short8v*)qb;
  short8v gA1 = *(const short8v*)pb;
  short8v aF2 = z8, gA2 = z8;
  if (kg < 2){ aF2 = aF1; gA2 = gA1; }

  float n2row[4];
  #pragma unroll
  for (int r=0;r<4;r++) n2row[r] = n2g[n0 + kg*4 + r];

  float gsum[4], mx[4], sm[4];
  #pragma unroll
  for (int r=0;r<4;r++){ gsum[r]=0.f; mx[r]=-1e30f; sm[r]=0.f; }

  const size_t hN = (size_t)h*NN;
  int mbase = w * 1024;

  // ---------------- sweep 1: row stats ----------------
  #pragma unroll 2
  for (int mt=0; mt<64; ++mt){
    int m0 = mbase + mt*16;
    int mm = m0 + cl;
    const unsigned short* kb = Kh + (hN + mm)*DE + (kg&1)*8;
    const unsigned short* pmb = Ph + (size_t)mm*DE + (kg&1)*8;
    short8v bF1 = *(const short8v*)kb;
    short8v gB1 = *(const short8v*)pmb;
    short8v bF2 = z8, gB2 = z8;
    if (kg < 2){
      bF2 = *(const short8v*)(Kl + (hN + mm)*DE + (kg&1)*8);
      gB2 = *(const short8v*)(Pl + (size_t)mm*DE + (kg&1)*8);
    }
    f32x4 zc = {};
    f32x4 sc = __builtin_amdgcn_mfma_f32_16x16x32_bf16(aF2, bF2, zc, 0,0,0);
    sc = __builtin_amdgcn_mfma_f32_16x16x32_bf16(aF1, bF1, sc, 0,0,0);
    f32x4 gc = __builtin_amdgcn_mfma_f32_16x16x32_bf16(gA2, gB2, zc, 0,0,0);
    gc = __builtin_amdgcn_mfma_f32_16x16x32_bf16(gA1, gB1, gc, 0,0,0);
    float n2m = n2g[m0 + cl];
    #pragma unroll
    for (int r=0;r<4;r++){
      float s = sc[r]*0.25f;
      float d2 = n2row[r] + n2m - 2.f*gc[r];
      float eg = __expf(__expf(-psi_v*d2));
      gsum[r] += eg;
      if (s > mx[r] + 8.f){
        sm[r] = sm[r]*__expf(mx[r]-s) + 1.f;
        mx[r] = s;
      } else {
        sm[r] += __expf(s - mx[r]);
      }
    }
  }
  #pragma unroll
  for (int off=1; off<16; off<<=1){
    #pragma unroll
    for (int r=0;r<4;r++){
      gsum[r] += __shfl_xor(gsum[r], off);
      float om = __shfl_xor(mx[r], off);
      float os = __shfl_xor(sm[r], off);
      float nm = fmaxf(mx[r], om);
      sm[r] = sm[r]*__expf(mx[r]-nm) + os*__expf(om-nm);
      mx[r] = nm;
    }
  }
  if (cl < 4){
    float g,m,s;
    if      (cl==0){ g=gsum[0]; m=mx[0]; s=sm[0]; }
    else if (cl==1){ g=gsum[1]; m=mx[1]; s=sm[1]; }
    else if (cl==2){ g=gsum[2]; m=mx[2]; s=sm[2]; }
    else           { g=gsum[3]; m=mx[3]; s=sm[3]; }
    int row = kg*4 + cl;
    st_g[w][row]=g; st_m[w][row]=m; st_s[w][row]=s;
  }
  __syncthreads();
  if (tid < 16){
    float G=0.f, M=-1e30f, S=0.f;
    #pragma unroll
    for (int ww=0; ww<4; ww++){
      G += st_g[ww][tid];
      float om = st_m[ww][tid], os = st_s[ww][tid];
      float nm = fmaxf(M, om);
      S = S*__expf(M-nm) + os*__expf(om-nm);
      M = nm;
    }
    fin_g[tid] = 1.f/G;
    fin_m[tid] = M;
    fin_s[tid] = 1.f/S;
  }
  __syncthreads();

  float fg[4], fm[4], fs[4];
  #pragma unroll
  for (int r=0;r<4;r++){
    fg[r]=fin_g[kg*4+r]; fm[r]=fin_m[kg*4+r]; fs[r]=fin_s[kg*4+r];
  }
  float a1 = alpha, a2 = 1.f - alpha;

  // ---------------- sweep 2: normalize + write ----------------
  for (int mt=0; mt<64; ++mt){
    int m0 = mbase + mt*16;
    int mm = m0 + cl;
    const unsigned short* kb = Kh + (hN + mm)*DE + (kg&1)*8;
    const unsigned short* pmb = Ph + (size_t)mm*DE + (kg&1)*8;
    short8v bF1 = *(const short8v*)kb;
    short8v gB1 = *(const short8v*)pmb;
    short8v bF2 = z8, gB2 = z8;
    if (kg < 2){
      bF2 = *(const short8v*)(Kl + (hN + mm)*DE + (kg&1)*8);
      gB2 = *(const short8v*)(Pl + (size_t)mm*DE + (kg&1)*8);
    }
    f32x4 zc = {};
    f32x4 sc = __builtin_amdgcn_mfma_f32_16x16x32_bf16(aF2, bF2, zc, 0,0,0);
    sc = __builtin_amdgcn_mfma_f32_16x16x32_bf16(aF1, bF1, sc, 0,0,0);
    f32x4 gc = __builtin_amdgcn_mfma_f32_16x16x32_bf16(gA2, gB2, zc, 0,0,0);
    gc = __builtin_amdgcn_mfma_f32_16x16x32_bf16(gA1, gB1, gc, 0,0,0);
    float n2m = n2g[m0 + cl];
    #pragma unroll
    for (int r=0;r<4;r++){
      float s = sc[r]*0.25f;
      float d2 = n2row[r] + n2m - 2.f*gc[r];
      float eg = __expf(__expf(-psi_v*d2));
      float ag  = eg * fg[r];
      float aat = __expf(s - fm[r]) * fs[r];
      float a = a1*ag + a2*aat;
      T[w][kg*4+r][(mt&3)*16 + cl] = f2bf(a);
    }
    if ((mt & 3) == 3){
      int row = lane >> 2, cgp = lane & 3;
      short8v v0 = *(const short8v*)&T[w][row][cgp*16];
      short8v v1 = *(const short8v*)&T[w][row][cgp*16+8];
      unsigned short* dst = A_all + hN*NN + (size_t)(n0+row)*NN + mbase + (mt&~3)*16 + cgp*16;
      *(short8v*)dst = v0;
      *(short8v*)(dst+8) = v1;
    }
  }
}

// ---- K4: x (B,N,L) f32 -> X[c][m] bf16 (c = b*64+l) -----------------------
__global__ __launch_bounds__(256) void k_xpose(const float* __restrict__ x,
                                               unsigned short* __restrict__ X){
  __shared__ float t[64][65];
  int b = blockIdx.y, n0 = blockIdx.x*64;
  int tid=threadIdx.x;
  int nr = tid>>2, lc=(tid&3)*16;
  const float* src = x + ((size_t)b*NN + n0 + nr)*LL + lc;
  #pragma unroll
  for (int j=0;j<16;j+=4){
    float4 v = *(const float4*)(src + j);
    t[nr][lc+j+0]=v.x; t[nr][lc+j+1]=v.y; t[nr][lc+j+2]=v.z; t[nr][lc+j+3]=v.w;
  }
  __syncthreads();
  int cl = tid>>2, mp=(tid&3)*16;
  short8v bufv[2];
  #pragma unroll
  for (int j=0;j<16;j++) bufv[j>>3][j&7] = (short)f2bf(t[mp+j][cl]);
  unsigned short* dst = X + (size_t)(b*LL+cl)*NN + n0 + mp;
  *(short8v*)dst = bufv[0];
  *(short8v*)(dst+8) = bufv[1];
}

// ---- K5: init out with k=0 (identity) term + bias -------------------------
__global__ void k_out0(const float* __restrict__ x, const float* __restrict__ W0c,
                       const float* __restrict__ bias_comb, float* __restrict__ out){
  int id = blockIdx.x*256+threadIdx.x;   // 65536 = B*N
  int n = id & (NN-1);
  float acc = bias_comb[n];
  const float* xp = x + (size_t)id*LL;
  #pragma unroll
  for (int l4=0;l4<LL;l4+=4){
    float4 xv = *(const float4*)(xp+l4);
    acc += xv.x*W0c[(size_t)(l4+0)*NN+n] + xv.y*W0c[(size_t)(l4+1)*NN+n]
         + xv.z*W0c[(size_t)(l4+2)*NN+n] + xv.w*W0c[(size_t)(l4+3)*NN+n];
  }
  out[id] = acc;
}

// ---- K6: Chebyshev GEMM step (256x256x64 8-phase, m201-template port) -----
// D[c][n] = sum_m Zin[c][m] * A[n][m]; 512 thr = 8 waves (2x4), wave 128x64.
// LDS linear (DMA), source-XOR swizzle slot^(row&7), read applies same XOR.
// Per K-tile: vmcnt(2) at top (counted, never 0 mid-loop), 4 phases of
// {ds_read frags || stage half-tile -> barrier -> lgkmcnt(0)+schedbar ->
//  setprio(1) 16 MFMA setprio(0) -> barrier}.
// y = scale*D - (HAS_PREV ? Yprev : 0); if STORE: Ynew = bf16(y);
// out[b][n] += sum_l y[(b,l)][n] * Wf_eff[h][kcheb][l][n]   (atomic)
template<int HAS_PREV, int STORE>
__global__ __launch_bounds__(512, 2) void k_cheb(
    const unsigned short* __restrict__ A_all,
    const unsigned short* __restrict__ Zin, size_t z_hs,
    const unsigned short* __restrict__ Yprev, size_t p_hs,
    unsigned short* __restrict__ Ynew, size_t y_hs,
    const float* __restrict__ Wf_eff, float* __restrict__ out,
    int kcheb, float scale)
{
  __shared__ __align__(16) unsigned short ZT[2][256][64];   // 64 KB
  __shared__ __align__(16) unsigned short AT[2][256][64];   // 64 KB
  int h = blockIdx.z;
  int n0 = blockIdx.x * 256;
  int c0 = blockIdx.y * 256;
  const unsigned short* Ah = A_all + (size_t)h*NN*NN;
  const unsigned short* Z  = Zin + z_hs*h;
  int tid = threadIdx.x;
  int lane = tid & 63, w = tid >> 6;     // 8 waves
  int wr = w >> 2, wc = w & 3;           // 2 (c) x 4 (n)
  f32x4 acc[8][4] = {};

  // staging: per gload line, wave w covers rows [64q+8w, +8), lane col slot
  // (lane&7), source col slot XOR'd by row&7 = lane>>3.
  int ssc = ((lane & 7) ^ (lane >> 3)) * 8;
  const unsigned short* gA0 = Ah + (size_t)(n0 + 8*w + (lane>>3))*NN + ssc;
  const unsigned short* gZ0 = Z  + (size_t)(c0 + 8*w + (lane>>3))*NN + ssc;

  int frow = lane & 15, fsl = lane >> 4;
  int fx = frow & 7;
  int s0 = ((0 + fsl) ^ fx) * 8;         // kk=0 swizzled hw offset
  int s1 = ((4 + fsl) ^ fx) * 8;         // kk=32

#define SG_A(buf, q, m0n) GLD_LDS16(gA0 + (size_t)(64*(q))*NN + (m0n), &AT[buf][64*(q)+8*w][0])
#define SG_Z(buf, q, m0n) GLD_LDS16(gZ0 + (size_t)(64*(q))*NN + (m0n), &ZT[buf][64*(q)+8*w][0])

  // prologue: full K-tile 0 -> buf 0 (8 gloads)
  SG_A(0,0,0); SG_A(0,1,0); SG_A(0,2,0); SG_A(0,3,0);
  SG_Z(0,0,0); SG_Z(0,1,0); SG_Z(0,2,0); SG_Z(0,3,0);

  for (int t = 0; t < 64; ++t) {
    int cur = t & 1;
    unsigned short (*zb)[64] = ZT[cur];
    unsigned short (*ab)[64] = AT[cur];
    int nm0 = (t+1)*64;
    // ---- tile top: stage A-half0 of next tile, counted drain ----
    if (t < 63) {
      SG_A(cur^1, 0, nm0); SG_A(cur^1, 1, nm0);
      asm volatile("s_waitcnt vmcnt(2)" ::: "memory");
    } else {
      asm volatile("s_waitcnt vmcnt(0)" ::: "memory");
    }
    __builtin_amdgcn_s_barrier();
    __builtin_amdgcn_sched_barrier(0);

    short8v a4[4], b4[4];

    // ---- phase 0: mh=0, kk=0 (load B kk0 + A mh0) ----
    #pragma unroll
    for (int j=0;j<4;j++) b4[j] = *(const short8v*)&ab[wc*64 + j*16 + frow][s0];
    #pragma unroll
    for (int i=0;i<4;i++) a4[i] = *(const short8v*)&zb[wr*128 + i*16 + frow][s0];
    __builtin_amdgcn_s_barrier();
    asm volatile("s_waitcnt lgkmcnt(0)" ::: "memory");
    __builtin_amdgcn_sched_barrier(0);
    __builtin_amdgcn_s_setprio(1);
    #pragma unroll
    for (int i=0;i<4;i++)
      #pragma unroll
      for (int j=0;j<4;j++)
        acc[i][j] = __builtin_amdgcn_mfma_f32_16x16x32_bf16(a4[i], b4[j], acc[i][j], 0,0,0);
    __builtin_amdgcn_s_setprio(0);
    __builtin_amdgcn_s_barrier();
    __builtin_amdgcn_sched_barrier(0);

    // ---- phase 1: mh=1, kk=0 (reuse B; stage A-half1) ----
    #pragma unroll
    for (int i=0;i<4;i++) a4[i] = *(const short8v*)&zb[wr*128 + 64 + i*16 + frow][s0];
    if (t < 63) { SG_A(cur^1, 2, nm0); SG_A(cur^1, 3, nm0); }
    __builtin_amdgcn_s_barrier();
    asm volatile("s_waitcnt lgkmcnt(0)" ::: "memory");
    __builtin_amdgcn_sched_barrier(0);
    __builtin_amdgcn_s_setprio(1);
    #pragma unroll
    for (int i=0;i<4;i++)
      #pragma unroll
      for (int j=0;j<4;j++)
        acc[4+i][j] = __builtin_amdgcn_mfma_f32_16x16x32_bf16(a4[i], b4[j], acc[4+i][j], 0,0,0);
    __builtin_amdgcn_s_setprio(0);
    __builtin_amdgcn_s_barrier();
    __builtin_amdgcn_sched_barrier(0);

    // ---- phase 2: mh=0, kk=32 (load B kk32 + A mh0; stage Z-half0) ----
    #pragma unroll
    for (int j=0;j<4;j++) b4[j] = *(const short8v*)&ab[wc*64 + j*16 + frow][s1];
    #pragma unroll
    for (int i=0;i<4;i++) a4[i] = *(const short8v*)&zb[wr*128 + i*16 + frow][s1];
    if (t < 63) { SG_Z(cur^1, 0, nm0); SG_Z(cur^1, 1, nm0); }
    __builtin_amdgcn_s_barrier();
    asm volatile("s_waitcnt lgkmcnt(0)" ::: "memory");
    __builtin_amdgcn_sched_barrier(0);
    __builtin_amdgcn_s_setprio(1);
    #pragma unroll
    for (int i=0;i<4;i++)
      #pragma unroll
      for (int j=0;j<4;j++)
        acc[i][j] = __builtin_amdgcn_mfma_f32_16x16x32_bf16(a4[i], b4[j], acc[i][j], 0,0,0);
    __builtin_amdgcn_s_setprio(0);
    __builtin_amdgcn_s_barrier();
    __builtin_amdgcn_sched_barrier(0);

    // ---- phase 3: mh=1, kk=32 (reuse B; stage Z-half1) ----
    #pragma unroll
    for (int i=0;i<4;i++) a4[i] = *(const short8v*)&zb[wr*128 + 64 + i*16 + frow][s1];
    if (t < 63) { SG_Z(cur^1, 2, nm0); SG_Z(cur^1, 3, nm0); }
    __builtin_amdgcn_s_barrier();
    asm volatile("s_waitcnt lgkmcnt(0)" ::: "memory");
    __builtin_amdgcn_sched_barrier(0);
    __builtin_amdgcn_s_setprio(1);
    #pragma unroll
    for (int i=0;i<4;i++)
      #pragma unroll
      for (int j=0;j<4;j++)
        acc[4+i][j] = __builtin_amdgcn_mfma_f32_16x16x32_bf16(a4[i], b4[j], acc[4+i][j], 0,0,0);
    __builtin_amdgcn_s_setprio(0);
    __builtin_amdgcn_s_barrier();
    __builtin_amdgcn_sched_barrier(0);
  }
#undef SG_A
#undef SG_Z

  // ---- epilogue ----
  int g4 = lane >> 4, nl = lane & 15;
  const float* wfb = Wf_eff + ((size_t)(h*4 + kcheb))*LL*NN;
  #pragma unroll
  for (int fn=0; fn<4; fn++){
    int n = n0 + wc*64 + fn*16 + nl;
    #pragma unroll
    for (int bb=0; bb<2; bb++){
      int bidx = (c0>>6) + wr*2 + bb;
      float psum = 0.f;
      #pragma unroll
      for (int f4=0; f4<4; f4++){
        int fm = bb*4 + f4;
        #pragma unroll
        for (int rr=0; rr<4; rr++){
          int c = c0 + wr*128 + fm*16 + 4*g4 + rr;
          size_t cn = (size_t)c*NN + n;
          float v = scale*acc[fm][fn][rr];
          if (HAS_PREV) v -= bf2f(Yprev[p_hs*h + cn]);
          if (STORE) Ynew[y_hs*h + cn] = f2bf(v);
          psum += v * wfb[(size_t)(c & 63)*NN + n];
        }
      }
      psum += __shfl_xor(psum, 16);
      psum += __shfl_xor(psum, 32);
      if (g4 == 0) atomicAdd(out + (size_t)bidx*NN + n, psum);
    }
  }
}

extern "C" void kernel_launch(void* const* d_in, const int* in_sizes, int n_in,
                              void* d_out, int out_size, void* d_ws, size_t ws_size,
                              hipStream_t stream) {
  const float* x         = (const float*)d_in[0];
  const float* psi_emb   = (const float*)d_in[1];
  const float* psi       = (const float*)d_in[2];
  const float* W_q       = (const float*)d_in[3];
  const float* W_k       = (const float*)d_in[4];
  const float* attn_alpha= (const float*)d_in[5];
  const float* F_w       = (const float*)d_in[6];
  const float* f_b       = (const float*)d_in[7];
  const float* head_mix  = (const float*)d_in[8];
  float* out = (float*)d_out;

  char* ws = (char*)d_ws;
  size_t off = 0;
  auto alloc = [&](size_t bytes)->void*{
    void* p = ws + off; off += (bytes + 255) & ~(size_t)255; return p;
  };
  unsigned short* A_all  = (unsigned short*)alloc((size_t)NH*NN*NN*2);
  unsigned short* X      = (unsigned short*)alloc((size_t)CC*NN*2);
  unsigned short* Y1     = (unsigned short*)alloc((size_t)NH*CC*NN*2);
  unsigned short* Y2     = (unsigned short*)alloc((size_t)NH*CC*NN*2);
  float* Wf_eff  = (float*)alloc((size_t)NH*4*LL*NN*4);
  float* W0c     = (float*)alloc((size_t)LL*NN*4);
  unsigned short* Qh = (unsigned short*)alloc((size_t)NH*NN*DE*2);
  unsigned short* Ql = (unsigned short*)alloc((size_t)NH*NN*DE*2);
  unsigned short* Kh = (unsigned short*)alloc((size_t)NH*NN*DE*2);
  unsigned short* Kl = (unsigned short*)alloc((size_t)NH*NN*DE*2);
  unsigned short* Ph = (unsigned short*)alloc((size_t)NN*DE*2);
  unsigned short* Pl = (unsigned short*)alloc((size_t)NN*DE*2);
  float* n2g     = (float*)alloc((size_t)NN*4);
  float* bias_c  = (float*)alloc((size_t)NN*4);

  k_prep<<<dim3(16), dim3(256), 0, stream>>>(psi_emb, W_q, W_k, f_b, head_mix,
                                             Qh, Ql, Kh, Kl, Ph, Pl, n2g, bias_c);
  k_wf<<<dim3(4096), dim3(256), 0, stream>>>(psi_emb, F_w, head_mix, Wf_eff, W0c);
  k_adj<<<dim3(256, NH), dim3(256), 0, stream>>>(Qh, Ql, Kh, Kl, Ph, Pl, n2g,
                                                 psi, attn_alpha, A_all);
  k_xpose<<<dim3(64, NB), dim3(256), 0, stream>>>(x, X);
  k_out0<<<dim3(256), dim3(256), 0, stream>>>(x, W0c, bias_c, out);

  dim3 gg(NN/256, CC/256, NH);   // 16 x 4 x 4 = 256 blocks, 1/CU
  size_t CN = (size_t)CC*NN;
  // step 1: Y1 = A @ X
  k_cheb<0,1><<<gg, dim3(512), 0, stream>>>(A_all, X, (size_t)0, X, (size_t)0,
                                            Y1, CN, Wf_eff, out, 1, 1.0f);
  // step 2: Y2 = 2 A @ Y1 - X
  k_cheb<1,1><<<gg, dim3(512), 0, stream>>>(A_all, Y1, CN, X, (size_t)0,
                                            Y2, CN, Wf_eff, out, 2, 2.0f);
  // step 3: Y3 = 2 A @ Y2 - Y1 (not stored; contracted in epilogue)
  k_cheb<1,0><<<gg, dim3(512), 0, stream>>>(A_all, Y2, CN, Y1, CN,
                                            Y2, (size_t)0, Wf_eff, out, 3, 2.0f);
  (void)in_sizes; (void)n_in; (void)out_size; (void)ws_size;
}

// Round 8
// 666.007 us; speedup vs baseline: 1.1494x; 1.1494x over previous
//
#include <hip/hip_runtime.h>
#include <hip/hip_bf16.h>

#define NN 4096   // nodes
#define DE 16     // embedding dim
#define NH 4      // heads
#define LL 64     // in_dim
#define NB 16     // batch
#define CC 1024   // NB*LL columns

typedef __attribute__((ext_vector_type(8))) short short8v;
typedef __attribute__((ext_vector_type(4))) float f32x4;

#define GLD_LDS16(gp, lp) __builtin_amdgcn_global_load_lds( \
    (const __attribute__((address_space(1))) unsigned int*)(gp), \
    (__attribute__((address_space(3))) unsigned int*)(lp), 16, 0, 0)

__device__ __forceinline__ unsigned short f2bf(float f){
  unsigned int u = __float_as_uint(f);
  u += 0x7fffu + ((u >> 16) & 1u);
  return (unsigned short)(u >> 16);
}
__device__ __forceinline__ float bf2f(unsigned short s){
  return __uint_as_float(((unsigned int)s) << 16);
}
__device__ __forceinline__ void get_mix(const float* hm, float* mw){
  float a=hm[0],b=hm[1],c=hm[2],d=hm[3];
  float m = fmaxf(fmaxf(a,b),fmaxf(c,d));
  float e0=__expf(a-m),e1=__expf(b-m),e2=__expf(c-m),e3=__expf(d-m);
  float inv = 1.0f/(e0+e1+e2+e3);
  mw[0]=e0*inv; mw[1]=e1*inv; mw[2]=e2*inv; mw[3]=e3*inv;
}

// ---- K1a: per-node prep: Q/K projections as bf16 hi/lo splits, psi splits,
//          ||p||^2, combined bias ------------------------------------------
__global__ void k_prep(const float* __restrict__ psi_emb, const float* __restrict__ W_q,
                       const float* __restrict__ W_k, const float* __restrict__ f_b,
                       const float* __restrict__ head_mix,
                       unsigned short* __restrict__ Qh, unsigned short* __restrict__ Ql,
                       unsigned short* __restrict__ Kh, unsigned short* __restrict__ Kl,
                       unsigned short* __restrict__ Ph, unsigned short* __restrict__ Pl,
                       float* __restrict__ n2g, float* __restrict__ bias_comb){
  int n = blockIdx.x*blockDim.x + threadIdx.x;
  if (n >= NN) return;
  float p[DE];
  float n2 = 0.f;
  unsigned short ph[DE], pl[DE];
  #pragma unroll
  for (int d=0;d<DE;d++){
    p[d] = psi_emb[n*DE+d];
    n2 += p[d]*p[d];
    ph[d] = f2bf(p[d]);
    pl[d] = f2bf(p[d] - bf2f(ph[d]));
  }
  n2g[n] = n2;
  *(short8v*)(Ph + n*DE)     = *(short8v*)ph;
  *(short8v*)(Ph + n*DE + 8) = *(short8v*)(ph+8);
  *(short8v*)(Pl + n*DE)     = *(short8v*)pl;
  *(short8v*)(Pl + n*DE + 8) = *(short8v*)(pl+8);
  float mw[NH]; get_mix(head_mix, mw);
  float bias = 0.f;
  for (int h=0; h<NH; h++){
    unsigned short qh[DE], ql[DE], kh[DE], kl[DE];
    #pragma unroll
    for (int m=0;m<DE;m++){
      float q=0.f,k=0.f;
      #pragma unroll
      for (int d=0;d<DE;d++){
        q += p[d]*W_q[(d*NH+h)*DE+m];
        k += p[d]*W_k[(d*NH+h)*DE+m];
      }
      qh[m]=f2bf(q); ql[m]=f2bf(q - bf2f(qh[m]));
      kh[m]=f2bf(k); kl[m]=f2bf(k - bf2f(kh[m]));
    }
    size_t base = ((size_t)h*NN + n)*DE;
    *(short8v*)(Qh+base)=*(short8v*)qh;   *(short8v*)(Qh+base+8)=*(short8v*)(qh+8);
    *(short8v*)(Ql+base)=*(short8v*)ql;   *(short8v*)(Ql+base+8)=*(short8v*)(ql+8);
    *(short8v*)(Kh+base)=*(short8v*)kh;   *(short8v*)(Kh+base+8)=*(short8v*)(kh+8);
    *(short8v*)(Kl+base)=*(short8v*)kl;   *(short8v*)(Kl+base+8)=*(short8v*)(kl+8);
    float bh=0.f;
    #pragma unroll
    for (int d=0;d<DE;d++) bh += p[d]*f_b[h*DE+d];
    bias += mw[h]*bh;
  }
  bias_comb[n]=bias;
}

// ---- K1b: per-node filter weights Wf_eff[h][k][l][n] (premult by mix_w) ---
__global__ void k_wf(const float* __restrict__ psi_emb, const float* __restrict__ F_w,
                     const float* __restrict__ head_mix,
                     float* __restrict__ Wf_eff, float* __restrict__ W0c){
  int id = blockIdx.x*256 + threadIdx.x;   // 2^20 threads: (k,l,n)
  int n = id & (NN-1);
  int kl = id >> 12;
  int l = kl & (LL-1);
  int k = kl >> 6;                          // 0..3
  float mw[NH]; get_mix(head_mix, mw);
  float p[DE];
  #pragma unroll
  for (int d=0;d<DE;d++) p[d]=psi_emb[n*DE+d];
  float s0=0.f;
  for (int h=0;h<NH;h++){
    float v=0.f;
    #pragma unroll
    for (int d=0;d<DE;d++) v += p[d]*F_w[((h*DE+d)*4+k)*LL+l];
    v *= mw[h];
    Wf_eff[(((size_t)(h*4+k))*LL+l)*NN+n]=v;
    s0 += v;
  }
  if (k==0) W0c[(size_t)l*NN+n]=s0;
}

// ---- K2: fused adjacency build (stats sweep + write sweep), MFMA scores ---
__global__ __launch_bounds__(256, 4) void k_adj(
    const unsigned short* __restrict__ Qh, const unsigned short* __restrict__ Ql,
    const unsigned short* __restrict__ Kh, const unsigned short* __restrict__ Kl,
    const unsigned short* __restrict__ Ph, const unsigned short* __restrict__ Pl,
    const float* __restrict__ n2g, const float* __restrict__ psi_p,
    const float* __restrict__ attn_alpha, unsigned short* __restrict__ A_all){
  __shared__ unsigned short T[4][16][72];
  __shared__ float st_g[4][16], st_m[4][16], st_s[4][16];
  __shared__ float fin_g[16], fin_m[16], fin_s[16];

  int tid = threadIdx.x;
  int lane = tid & 63, w = tid >> 6;
  int h = blockIdx.y;
  int n0 = blockIdx.x * 16;
  int kg = lane >> 4;          // k-group 0..3
  int cl = lane & 15;          // col-in-tile / row-in-frag
  float psi_v = psi_p[0];
  float alpha = 1.f/(1.f+__expf(-attn_alpha[0]));

  short8v z8 = {};
  int rown = n0 + cl;
  const unsigned short* qb = ((kg<2) ? Qh : Ql) + ((size_t)h*NN + rown)*DE + (kg&1)*8;
  const unsigned short* pb = ((kg<2) ? Ph : Pl) + (size_t)rown*DE + (kg&1)*8;
  short8v aF1 = *(const short8v*)qb;
  short8v gA1 = *(const short8v*)pb;
  short8v aF2 = z8, gA2 = z8;
  if (kg < 2){ aF2 = aF1; gA2 = gA1; }

  float n2row[4];
  #pragma unroll
  for (int r=0;r<4;r++) n2row[r] = n2g[n0 + kg*4 + r];

  float gsum[4], mx[4], sm[4];
  #pragma unroll
  for (int r=0;r<4;r++){ gsum[r]=0.f; mx[r]=-1e30f; sm[r]=0.f; }

  const size_t hN = (size_t)h*NN;
  int mbase = w * 1024;

  // ---------------- sweep 1: row stats ----------------
  #pragma unroll 2
  for (int mt=0; mt<64; ++mt){
    int m0 = mbase + mt*16;
    int mm = m0 + cl;
    const unsigned short* kb = Kh + (hN + mm)*DE + (kg&1)*8;
    const unsigned short* pmb = Ph + (size_t)mm*DE + (kg&1)*8;
    short8v bF1 = *(const short8v*)kb;
    short8v gB1 = *(const short8v*)pmb;
    short8v bF2 = z8, gB2 = z8;
    if (kg < 2){
      bF2 = *(const short8v*)(Kl + (hN + mm)*DE + (kg&1)*8);
      gB2 = *(const short8v*)(Pl + (size_t)mm*DE + (kg&1)*8);
    }
    f32x4 zc = {};
    f32x4 sc = __builtin_amdgcn_mfma_f32_16x16x32_bf16(aF2, bF2, zc, 0,0,0);
    sc = __builtin_amdgcn_mfma_f32_16x16x32_bf16(aF1, bF1, sc, 0,0,0);
    f32x4 gc = __builtin_amdgcn_mfma_f32_16x16x32_bf16(gA2, gB2, zc, 0,0,0);
    gc = __builtin_amdgcn_mfma_f32_16x16x32_bf16(gA1, gB1, gc, 0,0,0);
    float n2m = n2g[m0 + cl];
    #pragma unroll
    for (int r=0;r<4;r++){
      float s = sc[r]*0.25f;
      float d2 = n2row[r] + n2m - 2.f*gc[r];
      float eg = __expf(__expf(-psi_v*d2));
      gsum[r] += eg;
      if (s > mx[r] + 8.f){
        sm[r] = sm[r]*__expf(mx[r]-s) + 1.f;
        mx[r] = s;
      } else {
        sm[r] += __expf(s - mx[r]);
      }
    }
  }
  #pragma unroll
  for (int off=1; off<16; off<<=1){
    #pragma unroll
    for (int r=0;r<4;r++){
      gsum[r] += __shfl_xor(gsum[r], off);
      float om = __shfl_xor(mx[r], off);
      float os = __shfl_xor(sm[r], off);
      float nm = fmaxf(mx[r], om);
      sm[r] = sm[r]*__expf(mx[r]-nm) + os*__expf(om-nm);
      mx[r] = nm;
    }
  }
  if (cl < 4){
    float g,m,s;
    if      (cl==0){ g=gsum[0]; m=mx[0]; s=sm[0]; }
    else if (cl==1){ g=gsum[1]; m=mx[1]; s=sm[1]; }
    else if (cl==2){ g=gsum[2]; m=mx[2]; s=sm[2]; }
    else           { g=gsum[3]; m=mx[3]; s=sm[3]; }
    int row = kg*4 + cl;
    st_g[w][row]=g; st_m[w][row]=m; st_s[w][row]=s;
  }
  __syncthreads();
  if (tid < 16){
    float G=0.f, M=-1e30f, S=0.f;
    #pragma unroll
    for (int ww=0; ww<4; ww++){
      G += st_g[ww][tid];
      float om = st_m[ww][tid], os = st_s[ww][tid];
      float nm = fmaxf(M, om);
      S = S*__expf(M-nm) + os*__expf(om-nm);
      M = nm;
    }
    fin_g[tid] = 1.f/G;
    fin_m[tid] = M;
    fin_s[tid] = 1.f/S;
  }
  __syncthreads();

  float fg[4], fm[4], fs[4];
  #pragma unroll
  for (int r=0;r<4;r++){
    fg[r]=fin_g[kg*4+r]; fm[r]=fin_m[kg*4+r]; fs[r]=fin_s[kg*4+r];
  }
  float a1 = alpha, a2 = 1.f - alpha;

  // ---------------- sweep 2: normalize + write ----------------
  for (int mt=0; mt<64; ++mt){
    int m0 = mbase + mt*16;
    int mm = m0 + cl;
    const unsigned short* kb = Kh + (hN + mm)*DE + (kg&1)*8;
    const unsigned short* pmb = Ph + (size_t)mm*DE + (kg&1)*8;
    short8v bF1 = *(const short8v*)kb;
    short8v gB1 = *(const short8v*)pmb;
    short8v bF2 = z8, gB2 = z8;
    if (kg < 2){
      bF2 = *(const short8v*)(Kl + (hN + mm)*DE + (kg&1)*8);
      gB2 = *(const short8v*)(Pl + (size_t)mm*DE + (kg&1)*8);
    }
    f32x4 zc = {};
    f32x4 sc = __builtin_amdgcn_mfma_f32_16x16x32_bf16(aF2, bF2, zc, 0,0,0);
    sc = __builtin_amdgcn_mfma_f32_16x16x32_bf16(aF1, bF1, sc, 0,0,0);
    f32x4 gc = __builtin_amdgcn_mfma_f32_16x16x32_bf16(gA2, gB2, zc, 0,0,0);
    gc = __builtin_amdgcn_mfma_f32_16x16x32_bf16(gA1, gB1, gc, 0,0,0);
    float n2m = n2g[m0 + cl];
    #pragma unroll
    for (int r=0;r<4;r++){
      float s = sc[r]*0.25f;
      float d2 = n2row[r] + n2m - 2.f*gc[r];
      float eg = __expf(__expf(-psi_v*d2));
      float ag  = eg * fg[r];
      float aat = __expf(s - fm[r]) * fs[r];
      float a = a1*ag + a2*aat;
      T[w][kg*4+r][(mt&3)*16 + cl] = f2bf(a);
    }
    if ((mt & 3) == 3){
      int row = lane >> 2, cgp = lane & 3;
      short8v v0 = *(const short8v*)&T[w][row][cgp*16];
      short8v v1 = *(const short8v*)&T[w][row][cgp*16+8];
      unsigned short* dst = A_all + hN*NN + (size_t)(n0+row)*NN + mbase + (mt&~3)*16 + cgp*16;
      *(short8v*)dst = v0;
      *(short8v*)(dst+8) = v1;
    }
  }
}

// ---- K4: x (B,N,L) f32 -> X[c][m] bf16 (c = b*64+l) -----------------------
__global__ __launch_bounds__(256) void k_xpose(const float* __restrict__ x,
                                               unsigned short* __restrict__ X){
  __shared__ float t[64][65];
  int b = blockIdx.y, n0 = blockIdx.x*64;
  int tid=threadIdx.x;
  int nr = tid>>2, lc=(tid&3)*16;
  const float* src = x + ((size_t)b*NN + n0 + nr)*LL + lc;
  #pragma unroll
  for (int j=0;j<16;j+=4){
    float4 v = *(const float4*)(src + j);
    t[nr][lc+j+0]=v.x; t[nr][lc+j+1]=v.y; t[nr][lc+j+2]=v.z; t[nr][lc+j+3]=v.w;
  }
  __syncthreads();
  int cl = tid>>2, mp=(tid&3)*16;
  short8v bufv[2];
  #pragma unroll
  for (int j=0;j<16;j++) bufv[j>>3][j&7] = (short)f2bf(t[mp+j][cl]);
  unsigned short* dst = X + (size_t)(b*LL+cl)*NN + n0 + mp;
  *(short8v*)dst = bufv[0];
  *(short8v*)(dst+8) = bufv[1];
}

// ---- K5: init out with k=0 (identity) term + bias -------------------------
__global__ void k_out0(const float* __restrict__ x, const float* __restrict__ W0c,
                       const float* __restrict__ bias_comb, float* __restrict__ out){
  int id = blockIdx.x*256+threadIdx.x;   // 65536 = B*N
  int n = id & (NN-1);
  float acc = bias_comb[n];
  const float* xp = x + (size_t)id*LL;
  #pragma unroll
  for (int l4=0;l4<LL;l4+=4){
    float4 xv = *(const float4*)(xp+l4);
    acc += xv.x*W0c[(size_t)(l4+0)*NN+n] + xv.y*W0c[(size_t)(l4+1)*NN+n]
         + xv.z*W0c[(size_t)(l4+2)*NN+n] + xv.w*W0c[(size_t)(l4+3)*NN+n];
  }
  out[id] = acc;
}

// ---- K6: Chebyshev GEMM step (round-6 structure + static 2x unroll) -------
// Double-buffered global_load_lds staging, counted vmcnt(8), source-XOR
// swizzle (LDS slot s of row r holds global slot s^(r&7)); read applies same
// XOR. 2x-unrolled t-loop: buffer index static -> all 16 fragment addresses
// are 4 pre-computed VGPR bases + compile-time immediate offsets (kills the
// per-tile VALU address recompute that held round 6 at VALUBusy 45%).
// D[c][n] = sum_m Zin[c][m] * A[n][m]
// y = scale*D - (HAS_PREV ? Yprev : 0); if STORE: Ynew = bf16(y);
// out[b][n] += sum_l y[(b,l)][n] * Wf_eff[h][kcheb][l][n]   (atomic)
template<int HAS_PREV, int STORE>
__global__ __launch_bounds__(256) void k_cheb(
    const unsigned short* __restrict__ A_all,
    const unsigned short* __restrict__ Zin, size_t z_hs,
    const unsigned short* __restrict__ Yprev, size_t p_hs,
    unsigned short* __restrict__ Ynew, size_t y_hs,
    const float* __restrict__ Wf_eff, float* __restrict__ out,
    int kcheb, float scale)
{
  __shared__ __align__(16) unsigned short ZT[2][128][64];   // 2 x 16 KB
  __shared__ __align__(16) unsigned short AT[2][128][64];
  int h = blockIdx.z;
  int n0 = blockIdx.x * 128;
  int c0 = blockIdx.y * 128;
  const unsigned short* Ah = A_all + (size_t)h*NN*NN;
  const unsigned short* Z  = Zin + z_hs*h;
  int tid = threadIdx.x;
  int lane = tid & 63, w = tid >> 6;
  int wr = w >> 1, wc = w & 1;
  f32x4 acc[4][4] = {};

  // staging addresses (per-lane global, pre-swizzled source column)
  int lrow8 = lane >> 3;                         // 0..7 = dest row & 7
  int scol  = ((lane & 7) ^ lrow8) * 8;          // swizzled source col slot
  const unsigned short* gA = Ah + (size_t)(n0 + w*32 + lrow8)*NN + scol;
  const unsigned short* gZ = Z  + (size_t)(c0 + w*32 + lrow8)*NN + scol;

  // fragment read bases: 4 pointers, everything else is immediate offsets
  int frow = lane & 15;
  int rsw  = frow & 7;
  int fsl  = lane >> 4;
  int s0 = ((0 + fsl) ^ rsw) * 8;                // kk=0 swizzled slot (elems)
  int s1 = ((4 + fsl) ^ rsw) * 8;                // kk=32
  const unsigned short* zs0 = &ZT[0][wr*64 + frow][0] + s0;
  const unsigned short* zs1 = &ZT[0][wr*64 + frow][0] + s1;
  const unsigned short* as0 = &AT[0][wc*64 + frow][0] + s0;
  const unsigned short* as1 = &AT[0][wc*64 + frow][0] + s1;

#define STAGE(B, MO) do { \
    _Pragma("unroll") \
    for (int jj = 0; jj < 4; ++jj) { \
      GLD_LDS16(gA + (size_t)(8*jj)*NN + (MO), &AT[B][w*32 + 8*jj][0]); \
      GLD_LDS16(gZ + (size_t)(8*jj)*NN + (MO), &ZT[B][w*32 + 8*jj][0]); \
    } \
  } while(0)

#define COMPUTE(B) do { \
    short8v af0[4], af1[4], bf0[4], bf1[4]; \
    _Pragma("unroll") \
    for (int i=0;i<4;i++){ \
      af0[i] = *(const short8v*)(zs0 + (B)*8192 + i*1024); \
      af1[i] = *(const short8v*)(zs1 + (B)*8192 + i*1024); \
      bf0[i] = *(const short8v*)(as0 + (B)*8192 + i*1024); \
      bf1[i] = *(const short8v*)(as1 + (B)*8192 + i*1024); \
    } \
    _Pragma("unroll") \
    for (int i=0;i<4;i++) \
      _Pragma("unroll") \
      for (int j=0;j<4;j++) \
        acc[i][j] = __builtin_amdgcn_mfma_f32_16x16x32_bf16(af0[i], bf0[j], acc[i][j], 0,0,0); \
    _Pragma("unroll") \
    for (int i=0;i<4;i++) \
      _Pragma("unroll") \
      for (int j=0;j<4;j++) \
        acc[i][j] = __builtin_amdgcn_mfma_f32_16x16x32_bf16(af1[i], bf1[j], acc[i][j], 0,0,0); \
  } while(0)

#define BARRIER() do { __builtin_amdgcn_s_barrier(); __builtin_amdgcn_sched_barrier(0); } while(0)

  STAGE(0, 0);            // prologue: tile 0 -> buf0
  int mo = 64;
  for (int tp = 0; tp < 31; ++tp) {
    // even tile: read buf0, stage buf1
    BARRIER();
    STAGE(1, mo); mo += 64;
    asm volatile("s_waitcnt vmcnt(8)" ::: "memory");
    BARRIER();
    COMPUTE(0);
    // odd tile: read buf1, stage buf0
    BARRIER();
    STAGE(0, mo); mo += 64;
    asm volatile("s_waitcnt vmcnt(8)" ::: "memory");
    BARRIER();
    COMPUTE(1);
  }
  // t = 62: read buf0, stage buf1 (last tile)
  BARRIER();
  STAGE(1, mo);
  asm volatile("s_waitcnt vmcnt(8)" ::: "memory");
  BARRIER();
  COMPUTE(0);
  // t = 63: read buf1, no stage
  BARRIER();
  asm volatile("s_waitcnt vmcnt(0)" ::: "memory");
  BARRIER();
  COMPUTE(1);

#undef STAGE
#undef COMPUTE
#undef BARRIER

  // epilogue
  int b = (c0 >> 6) + wr;
  int g4 = lane >> 4, nl = lane & 15;
  #pragma unroll
  for (int j=0;j<4;j++){
    int n = n0 + wc*64 + j*16 + nl;
    float psum = 0.f;
    #pragma unroll
    for (int i=0;i<4;i++){
      #pragma unroll
      for (int r=0;r<4;r++){
        int lx = i*16 + 4*g4 + r;
        size_t cn = (size_t)(b*64 + lx)*NN + n;
        float v = scale*acc[i][j][r];
        if (HAS_PREV) v -= bf2f(Yprev[p_hs*h + cn]);
        if (STORE) Ynew[y_hs*h + cn] = f2bf(v);
        psum += v * Wf_eff[(((size_t)(h*4 + kcheb))*LL + lx)*NN + n];
      }
    }
    psum += __shfl_xor(psum, 16);
    psum += __shfl_xor(psum, 32);
    if (g4 == 0) atomicAdd(out + (size_t)b*NN + n, psum);
  }
}

extern "C" void kernel_launch(void* const* d_in, const int* in_sizes, int n_in,
                              void* d_out, int out_size, void* d_ws, size_t ws_size,
                              hipStream_t stream) {
  const float* x         = (const float*)d_in[0];
  const float* psi_emb   = (const float*)d_in[1];
  const float* psi       = (const float*)d_in[2];
  const float* W_q       = (const float*)d_in[3];
  const float* W_k       = (const float*)d_in[4];
  const float* attn_alpha= (const float*)d_in[5];
  const float* F_w       = (const float*)d_in[6];
  const float* f_b       = (const float*)d_in[7];
  const float* head_mix  = (const float*)d_in[8];
  float* out = (float*)d_out;

  char* ws = (char*)d_ws;
  size_t off = 0;
  auto alloc = [&](size_t bytes)->void*{
    void* p = ws + off; off += (bytes + 255) & ~(size_t)255; return p;
  };
  unsigned short* A_all  = (unsigned short*)alloc((size_t)NH*NN*NN*2);
  unsigned short* X      = (unsigned short*)alloc((size_t)CC*NN*2);
  unsigned short* Y1     = (unsigned short*)alloc((size_t)NH*CC*NN*2);
  unsigned short* Y2     = (unsigned short*)alloc((size_t)NH*CC*NN*2);
  float* Wf_eff  = (float*)alloc((size_t)NH*4*LL*NN*4);
  float* W0c     = (float*)alloc((size_t)LL*NN*4);
  unsigned short* Qh = (unsigned short*)alloc((size_t)NH*NN*DE*2);
  unsigned short* Ql = (unsigned short*)alloc((size_t)NH*NN*DE*2);
  unsigned short* Kh = (unsigned short*)alloc((size_t)NH*NN*DE*2);
  unsigned short* Kl = (unsigned short*)alloc((size_t)NH*NN*DE*2);
  unsigned short* Ph = (unsigned short*)alloc((size_t)NN*DE*2);
  unsigned short* Pl = (unsigned short*)alloc((size_t)NN*DE*2);
  float* n2g     = (float*)alloc((size_t)NN*4);
  float* bias_c  = (float*)alloc((size_t)NN*4);

  k_prep<<<dim3(16), dim3(256), 0, stream>>>(psi_emb, W_q, W_k, f_b, head_mix,
                                             Qh, Ql, Kh, Kl, Ph, Pl, n2g, bias_c);
  k_wf<<<dim3(4096), dim3(256), 0, stream>>>(psi_emb, F_w, head_mix, Wf_eff, W0c);
  k_adj<<<dim3(256, NH), dim3(256), 0, stream>>>(Qh, Ql, Kh, Kl, Ph, Pl, n2g,
                                                 psi, attn_alpha, A_all);
  k_xpose<<<dim3(64, NB), dim3(256), 0, stream>>>(x, X);
  k_out0<<<dim3(256), dim3(256), 0, stream>>>(x, W0c, bias_c, out);

  dim3 gg(32, 8, NH);
  size_t CN = (size_t)CC*NN;
  // step 1: Y1 = A @ X
  k_cheb<0,1><<<gg, dim3(256), 0, stream>>>(A_all, X, (size_t)0, X, (size_t)0,
                                            Y1, CN, Wf_eff, out, 1, 1.0f);
  // step 2: Y2 = 2 A @ Y1 - X
  k_cheb<1,1><<<gg, dim3(256), 0, stream>>>(A_all, Y1, CN, X, (size_t)0,
                                            Y2, CN, Wf_eff, out, 2, 2.0f);
  // step 3: Y3 = 2 A @ Y2 - Y1 (not stored; contracted in epilogue)
  k_cheb<1,0><<<gg, dim3(256), 0, stream>>>(A_all, Y2, CN, Y1, CN,
                                            Y2, (size_t)0, Wf_eff, out, 3, 2.0f);
  (void)in_sizes; (void)n_in; (void)out_size; (void)ws_size;
}